// Round 4
// baseline (1871.804 us; speedup 1.0000x reference)
//
#include <hip/hip_runtime.h>
#include <hip/hip_bf16.h>

// ---------------------------------------------------------------------------
// SwinBlock fp32 for MI355X — workspace-adaptive chunked version.
// B=32 H=W=56 C=192 ws=7 shift=3 NH=6 hd=32; T=100352 token-rows.
// Workspace layout: [stats1 2T][stats2 2T][shared big buffer]
//   big buffer holds qkv-chunk (rowsA x 576) OR mlp-hidden-chunk (rowsM x 768)
//   chunk counts chosen at launch from ws_size (constant -> capture-safe).
// ---------------------------------------------------------------------------

#define T_ROWS   100352      // 2048 windows * 49 tokens
#define C_DIM    192
#define N_WIN    2048

// window token r=(w,n) -> image pixel index (same map for gather and scatter)
__device__ __forceinline__ int map_token(int r) {
    int w = r / 49, n = r % 49;
    int b = w >> 6, widx = w & 63;
    int wi = widx >> 3, wj = widx & 7;
    int pi = n / 7, pj = n % 7;
    int row = wi * 7 + pi + 3; if (row >= 56) row -= 56;
    int col = wj * 7 + pj + 3; if (col >= 56) col -= 56;
    return b * 3136 + row * 56 + col;
}

// ---------------- per-row LN stats (mu, rstd) --------------------------------
__global__ __launch_bounds__(256) void ln_stats(
        const float* __restrict__ h, float* __restrict__ stats) {
    int row  = blockIdx.x * 4 + (threadIdx.x >> 6);
    int lane = threadIdx.x & 63;
    const float* sp = h + (size_t)row * C_DIM;
    float v0 = sp[lane], v1 = sp[lane + 64], v2 = sp[lane + 128];
    float s  = v0 + v1 + v2;
    float s2 = v0 * v0 + v1 * v1 + v2 * v2;
    #pragma unroll
    for (int off = 32; off; off >>= 1) {
        s  += __shfl_xor(s,  off);
        s2 += __shfl_xor(s2, off);
    }
    if (lane == 0) {
        float mu  = s * (1.0f / 192.0f);
        float var = s2 * (1.0f / 192.0f) - mu * mu;
        stats[(size_t)row * 2]     = mu;
        stats[(size_t)row * 2 + 1] = rsqrtf(var + 1e-5f);
    }
}

// ---------------- fp32 GEMM 128x64x8, 256 threads, 8x4 acc per thread --------
// MODE 0: qkv  — A row = map_token(row_off + r) into x, LN1 on the fly;
//               C = chunk-local rows, stride 576
// MODE 1: proj — A chunk-local rows (stride 576);
//               C[map_token(row_off+r)] = acc + bias + x[same]
// MODE 2: mlp1 — A row-aligned w/ LN2 (pre-offset ptrs); C = gelu(acc+bias)
// MODE 3: mlp2 — A row-aligned; C = acc + bias + res[r] (pre-offset ptrs)
template<int MODE>
__global__ __launch_bounds__(256) void gemm128x64(
        const float* __restrict__ A, const float* __restrict__ B,
        const float* __restrict__ bias, float* __restrict__ C,
        int K, int N, int Astride, int Bstride, int Cstride,
        const float* __restrict__ res,
        const float* __restrict__ stats,
        const float* __restrict__ lng, const float* __restrict__ lnb,
        int row_off) {
    __shared__ float As[2][8][128];
    __shared__ float Bs[2][8][64];
    const int tid = threadIdx.x;
    const int m0 = blockIdx.y * 128;
    const int n0 = blockIdx.x * 64;
    const int tn = tid & 15, tm = tid >> 4;
    const int arow = tid >> 1;          // 0..127
    const int acol = (tid & 1) * 4;     // 0 or 4
    const int brow = tid >> 5;          // 0..7
    const int bcol = (tid & 31) * 2;    // 0..62

    int asrc = m0 + arow;               // A row index (local)
    if (MODE == 0) asrc = map_token(row_off + m0 + arow);
    float mu = 0.f, rstd = 0.f;
    if (MODE == 0 || MODE == 2) {
        mu   = stats[(size_t)asrc * 2];
        rstd = stats[(size_t)asrc * 2 + 1];
    }

    float acc[8][4];
    #pragma unroll
    for (int i = 0; i < 8; ++i)
        #pragma unroll
        for (int j = 0; j < 4; ++j) acc[i][j] = 0.f;

    const float* aptr = A + (size_t)asrc * Astride + acol;
    const float* bptr = B + (size_t)brow * Bstride + n0 + bcol;

    auto loadA = [&](int k0) {
        float4 v = *(const float4*)(aptr + k0);
        if (MODE == 0 || MODE == 2) {
            float4 g4 = *(const float4*)(lng + k0 + acol);
            float4 b4 = *(const float4*)(lnb + k0 + acol);
            v.x = (v.x - mu) * rstd * g4.x + b4.x;
            v.y = (v.y - mu) * rstd * g4.y + b4.y;
            v.z = (v.z - mu) * rstd * g4.z + b4.z;
            v.w = (v.w - mu) * rstd * g4.w + b4.w;
        }
        return v;
    };
    auto loadB = [&](int k0) {
        return *(const float2*)(bptr + (size_t)k0 * Bstride);
    };

    // prime buffer 0
    float4 av = loadA(0);
    float2 bv = loadB(0);
    As[0][acol + 0][arow] = av.x;
    As[0][acol + 1][arow] = av.y;
    As[0][acol + 2][arow] = av.z;
    As[0][acol + 3][arow] = av.w;
    Bs[0][brow][bcol]     = bv.x;
    Bs[0][brow][bcol + 1] = bv.y;
    __syncthreads();

    const int nt = K >> 3;
    for (int t = 0; t < nt; ++t) {
        const int buf = t & 1;
        float4 an; float2 bn;
        if (t + 1 < nt) {
            an = loadA((t + 1) << 3);
            bn = loadB((t + 1) << 3);
        }
        #pragma unroll
        for (int kk = 0; kk < 8; ++kk) {
            const float4 a0 = *(const float4*)&As[buf][kk][tm * 4];
            const float4 a1 = *(const float4*)&As[buf][kk][64 + tm * 4];
            const float4 b0 = *(const float4*)&Bs[buf][kk][tn * 4];
            const float avv[8] = {a0.x, a0.y, a0.z, a0.w, a1.x, a1.y, a1.z, a1.w};
            const float bvv[4] = {b0.x, b0.y, b0.z, b0.w};
            #pragma unroll
            for (int i = 0; i < 8; ++i)
                #pragma unroll
                for (int j = 0; j < 4; ++j)
                    acc[i][j] = fmaf(avv[i], bvv[j], acc[i][j]);
        }
        if (t + 1 < nt) {
            const int nb = buf ^ 1;
            As[nb][acol + 0][arow] = an.x;
            As[nb][acol + 1][arow] = an.y;
            As[nb][acol + 2][arow] = an.z;
            As[nb][acol + 3][arow] = an.w;
            Bs[nb][brow][bcol]     = bn.x;
            Bs[nb][brow][bcol + 1] = bn.y;
            __syncthreads();
        }
    }

    // epilogue
    const int col = n0 + tn * 4;
    const float4 bias4 = *(const float4*)(bias + col);
    #pragma unroll
    for (int gi = 0; gi < 2; ++gi) {
        #pragma unroll
        for (int i = 0; i < 4; ++i) {
            const int r = m0 + gi * 64 + tm * 4 + i;
            float4 o;
            o.x = acc[gi * 4 + i][0] + bias4.x;
            o.y = acc[gi * 4 + i][1] + bias4.y;
            o.z = acc[gi * 4 + i][2] + bias4.z;
            o.w = acc[gi * 4 + i][3] + bias4.w;
            if (MODE == 0) {
                *(float4*)&C[(size_t)r * Cstride + col] = o;
            } else if (MODE == 1) {
                const int dst = map_token(row_off + r);
                const float4 x4 = *(const float4*)&res[(size_t)dst * C_DIM + col];
                o.x += x4.x; o.y += x4.y; o.z += x4.z; o.w += x4.w;
                *(float4*)&C[(size_t)dst * C_DIM + col] = o;
            } else if (MODE == 2) {
                o.x = 0.5f * o.x * (1.0f + erff(o.x * 0.70710678118654752f));
                o.y = 0.5f * o.y * (1.0f + erff(o.y * 0.70710678118654752f));
                o.z = 0.5f * o.z * (1.0f + erff(o.z * 0.70710678118654752f));
                o.w = 0.5f * o.w * (1.0f + erff(o.w * 0.70710678118654752f));
                *(float4*)&C[(size_t)r * Cstride + col] = o;
            } else {  // MODE 3: row-aligned residual add
                const float4 r4 = *(const float4*)&res[(size_t)r * C_DIM + col];
                o.x += r4.x; o.y += r4.y; o.z += r4.z; o.w += r4.w;
                *(float4*)&C[(size_t)r * Cstride + col] = o;
            }
        }
    }
}

// ---------------- window attention: one (window, head) per block -------------
// Operates on a chunk of the qkv buffer; writes output IN PLACE into its own
// (window,head) q-slice (staged to LDS before overwrite).
__global__ __launch_bounds__(256) void attn_kernel(
        float* __restrict__ qkv, const float* __restrict__ rpb, int w0) {
    const int lw = blockIdx.x / 6;      // chunk-local window
    const int h  = blockIdx.x % 6;
    const int w  = w0 + lw;             // global window (for mask coords)
    __shared__ float q[49][33], k[49][33], v[49][33];
    __shared__ float S[49][50];
    __shared__ float rsum[49];
    const int tid = threadIdx.x;
    const float scale = 0.17677669529663687f;   // 1/sqrt(32)
    float* base = qkv + (size_t)lw * 49 * 576 + h * 32;
    for (int i = tid; i < 49 * 32; i += 256) {
        const int n = i >> 5, c = i & 31;
        q[n][c] = base[n * 576 + c];
        k[n][c] = base[n * 576 + 192 + c];
        v[n][c] = base[n * 576 + 384 + c];
    }
    __syncthreads();
    const int widx = w & 63;
    const int wi = widx >> 3, wj = widx & 7;
    for (int e = tid; e < 49 * 49; e += 256) {
        const int n = e / 49, m = e % 49;
        float acc = 0.f;
        #pragma unroll
        for (int c = 0; c < 32; ++c) acc = fmaf(q[n][c], k[m][c], acc);
        acc *= scale;
        const int pin = n / 7, pjn = n % 7, pim = m / 7, pjm = m % 7;
        acc += rpb[((pin - pim + 6) * 13 + (pjn - pjm + 6)) * 6 + h];
        // shift mask on shifted-image coordinates
        const int rn = wi * 7 + pin, cn = wj * 7 + pjn;
        const int rm = wi * 7 + pim, cm = wj * 7 + pjm;
        const int zn = (rn < 49 ? 0 : (rn < 53 ? 1 : 2)) * 3 + (cn < 49 ? 0 : (cn < 53 ? 1 : 2));
        const int zm = (rm < 49 ? 0 : (rm < 53 ? 1 : 2)) * 3 + (cm < 49 ? 0 : (cm < 53 ? 1 : 2));
        if (zn != zm) acc -= 100.0f;
        S[n][m] = acc;
    }
    __syncthreads();
    if (tid < 49) {
        float mx = -1e30f;
        #pragma unroll 7
        for (int m2 = 0; m2 < 49; ++m2) mx = fmaxf(mx, S[tid][m2]);
        float sum = 0.f;
        #pragma unroll 7
        for (int m2 = 0; m2 < 49; ++m2) {
            const float e2 = expf(S[tid][m2] - mx);
            S[tid][m2] = e2;
            sum += e2;
        }
        rsum[tid] = 1.0f / sum;
    }
    __syncthreads();
    for (int e = tid; e < 49 * 32; e += 256) {
        const int n = e >> 5, c = e & 31;
        float acc = 0.f;
        #pragma unroll 7
        for (int m2 = 0; m2 < 49; ++m2) acc = fmaf(S[n][m2], v[m2][c], acc);
        base[n * 576 + c] = acc * rsum[n];   // overwrite own q-slice
    }
}

// ---------------------------------------------------------------------------
extern "C" void kernel_launch(void* const* d_in, const int* in_sizes, int n_in,
                              void* d_out, int out_size, void* d_ws, size_t ws_size,
                              hipStream_t stream) {
    const float* x      = (const float*)d_in[0];
    const float* n1g    = (const float*)d_in[1];
    const float* n1b    = (const float*)d_in[2];
    const float* n2g    = (const float*)d_in[3];
    const float* n2b    = (const float*)d_in[4];
    const float* qkv_w  = (const float*)d_in[5];
    const float* qkv_b  = (const float*)d_in[6];
    const float* proj_w = (const float*)d_in[7];
    const float* proj_b = (const float*)d_in[8];
    const float* rpb    = (const float*)d_in[9];
    const float* mlp_w1 = (const float*)d_in[10];
    const float* mlp_b1 = (const float*)d_in[11];
    const float* mlp_w2 = (const float*)d_in[12];
    const float* mlp_b2 = (const float*)d_in[13];
    float* out = (float*)d_out;

    float* wsf = (float*)d_ws;
    float* stats1 = wsf;                      // 2*T floats
    float* stats2 = wsf + 2 * T_ROWS;         // 2*T floats
    float* bigbuf = wsf + 4 * T_ROWS;         // shared chunk buffer
    const size_t avail = (ws_size > (size_t)4 * T_ROWS * 4)
                       ? (ws_size - (size_t)4 * T_ROWS * 4) : 0;

    // choose chunk counts from available workspace (ws_size is constant
    // across calls -> identical work every call; capture-safe)
    int nc = 1;   // attention chunks over windows
    while (nc < 16 && (size_t)(N_WIN / nc) * 49 * 576 * 4 > avail) nc <<= 1;
    int nm = 1;   // mlp chunks over rows
    while (nm < 16 && (size_t)(T_ROWS / nm) * 768 * 4 > avail) nm <<= 1;

    const int winC  = N_WIN / nc;      // windows per attention chunk
    const int rowsC = winC * 49;       // rows per attention chunk (mult of 128)
    const int rowsM = T_ROWS / nm;     // rows per mlp chunk (mult of 128)

    const dim3 blk(256);

    // 1. LN1 stats on x rows
    ln_stats<<<dim3(T_ROWS / 4), blk, 0, stream>>>(x, stats1);

    // 2-4. attention path, chunked over windows
    for (int c = 0; c < nc; ++c) {
        const int row_off = c * rowsC;
        const int w0      = c * winC;
        gemm128x64<0><<<dim3(9, rowsC / 128), blk, 0, stream>>>(
            x, qkv_w, qkv_b, bigbuf, 192, 576, 192, 576, 576,
            nullptr, stats1, n1g, n1b, row_off);
        attn_kernel<<<dim3(winC * 6), blk, 0, stream>>>(bigbuf, rpb, w0);
        gemm128x64<1><<<dim3(3, rowsC / 128), blk, 0, stream>>>(
            bigbuf, proj_w, proj_b, out, 192, 192, 576, 192, 192,
            x, nullptr, nullptr, nullptr, row_off);
    }

    // 5. LN2 stats on h rows (h lives in d_out)
    ln_stats<<<dim3(T_ROWS / 4), blk, 0, stream>>>(out, stats2);

    // 6-7. MLP, chunked over rows; overwrites d_out rows with final result
    for (int c = 0; c < nm; ++c) {
        const int ro = c * rowsM;
        gemm128x64<2><<<dim3(12, rowsM / 128), blk, 0, stream>>>(
            out + (size_t)ro * C_DIM, mlp_w1, mlp_b1, bigbuf,
            192, 768, 192, 768, 768,
            nullptr, stats2 + (size_t)ro * 2, n2g, n2b, 0);
        gemm128x64<3><<<dim3(3, rowsM / 128), blk, 0, stream>>>(
            bigbuf, mlp_w2, mlp_b2, out + (size_t)ro * C_DIM,
            768, 192, 768, 192, 192,
            out + (size_t)ro * C_DIM, nullptr, nullptr, nullptr, 0);
    }
}